// Round 1
// baseline (11886.716 us; speedup 1.0000x reference)
//
#include <hip/hip_runtime.h>
#include <hip/hip_bf16.h>
#include <math.h>

typedef __hip_bfloat16 bf16;
typedef __attribute__((ext_vector_type(8))) __bf16 bf16x8;
typedef __attribute__((ext_vector_type(4))) float f32x4;

#define SEQ 512
#define HID 768
#define NHEADS 12
#define DHEAD 64
#define FFDIM 3072
#define NLAYER 12
#define BATCH 4
#define NTOK 2048      /* BATCH*SEQ */
#define EXTROWS 2560   /* NTOK + 512 (rel_e) */
#define SPAN2 512      /* 2*att_span */
#define NCLS 9

#define ATT_SCALE 0.07216878364870322f  /* 1/sqrt(64*3) */
#define NEG_BIG  -3.402823466e38f

// dtype-polymorphic loads/stores
__device__ __forceinline__ float ldv(const float* p, size_t i) { return p[i]; }
__device__ __forceinline__ float ldv(const bf16* p, size_t i) { return __bfloat162float(p[i]); }
__device__ __forceinline__ void stv(float* p, size_t i, float v) { p[i] = v; }
__device__ __forceinline__ void stv(bf16* p, size_t i, float v) { p[i] = __float2bfloat16(v); }

template <typename T> struct WantFlag { static constexpr int v = 0; };
template <> struct WantFlag<bf16>  { static constexpr int v = 1; };

#define GUARD if (dflag[0] != want) return;

__device__ __forceinline__ f32x4 mfma16(bf16x8 a, bf16x8 b, f32x4 c) {
    return __builtin_amdgcn_mfma_f32_16x16x32_bf16(a, b, c, 0, 0, 0);
}

// ---------------- dtype detect: emb_ln_s is all-ones ----------------
__global__ void detect_kernel(const void* probe, int* flag) {
    if (threadIdx.x == 0 && blockIdx.x == 0) {
        unsigned short v = ((const unsigned short*)probe)[0];
        flag[0] = (v == 0x3F80) ? 1 : 0;   // bf16(1.0)=0x3F80 ; fp32(1.0) low half = 0x0000
    }
}

// ---------------- reductions ----------------
__device__ __forceinline__ void block_reduce_sum2(float& a, float& b, float* red) {
    for (int off = 32; off > 0; off >>= 1) {
        a += __shfl_down(a, off, 64);
        b += __shfl_down(b, off, 64);
    }
    int wave = threadIdx.x >> 6, lane = threadIdx.x & 63;
    if (lane == 0) { red[wave * 2] = a; red[wave * 2 + 1] = b; }
    __syncthreads();
    if (threadIdx.x == 0) {
        red[8] = red[0] + red[2] + red[4] + red[6];
        red[9] = red[1] + red[3] + red[5] + red[7];
    }
    __syncthreads();
    a = red[8]; b = red[9];
}

__device__ __forceinline__ float block_max(float v, float* red) {
    for (int off = 32; off > 0; off >>= 1) v = fmaxf(v, __shfl_down(v, off, 64));
    int wave = threadIdx.x >> 6, lane = threadIdx.x & 63;
    if (lane == 0) red[wave] = v;
    __syncthreads();
    if (threadIdx.x == 0) red[8] = fmaxf(fmaxf(red[0], red[1]), fmaxf(red[2], red[3]));
    __syncthreads();
    float r = red[8];
    __syncthreads();
    return r;
}

__device__ __forceinline__ float block_sum(float v, float* red) {
    for (int off = 32; off > 0; off >>= 1) v += __shfl_down(v, off, 64);
    int wave = threadIdx.x >> 6, lane = threadIdx.x & 63;
    if (lane == 0) red[wave] = v;
    __syncthreads();
    if (threadIdx.x == 0) red[8] = red[0] + red[1] + red[2] + red[3];
    __syncthreads();
    float r = red[8];
    __syncthreads();
    return r;
}

// ---------------- embeddings ----------------
template <typename T>
__global__ __launch_bounds__(256) void embed_ln_kernel(
    const int* __restrict__ dflag, int want,
    const int* __restrict__ ids, const int* __restrict__ amask,
    const T* __restrict__ we, const T* __restrict__ te,
    const T* __restrict__ g, const T* __restrict__ bb, float* __restrict__ x) {
    GUARD
    int r = blockIdx.x;
    int id = ids[r];
    __shared__ float red[10];
    float v[3], sum = 0.f, sq = 0.f;
    for (int i = 0; i < 3; i++) {
        int j = threadIdx.x + i * 256;
        float e = ldv(we, (size_t)id * HID + j) + ldv(te, j);
        v[i] = e; sum += e; sq += e * e;
    }
    block_reduce_sum2(sum, sq, red);
    float mu = sum * (1.f / HID);
    float var = sq * (1.f / HID) - mu * mu;
    float inv = 1.f / sqrtf(var + 1e-7f);
    float mf = (float)amask[r];
    for (int i = 0; i < 3; i++) {
        int j = threadIdx.x + i * 256;
        x[(size_t)r * HID + j] = ((v[i] - mu) * inv * ldv(g, j) + ldv(bb, j)) * mf;
    }
}

template <typename T>
__global__ __launch_bounds__(256) void rel_ln_kernel(
    const int* __restrict__ dflag, int want,
    const T* __restrict__ re, const T* __restrict__ g, const T* __restrict__ bb,
    float* __restrict__ x) {
    GUARD
    int r = blockIdx.x;
    __shared__ float red[10];
    float v[3], sum = 0.f, sq = 0.f;
    for (int i = 0; i < 3; i++) {
        int j = threadIdx.x + i * 256;
        float e = ldv(re, (size_t)r * HID + j);
        v[i] = e; sum += e; sq += e * e;
    }
    block_reduce_sum2(sum, sq, red);
    float mu = sum * (1.f / HID);
    float var = sq * (1.f / HID) - mu * mu;
    float inv = 1.f / sqrtf(var + 1e-7f);
    for (int i = 0; i < 3; i++) {
        int j = threadIdx.x + i * 256;
        x[(size_t)(NTOK + r) * HID + j] = (v[i] - mu) * inv * ldv(g, j) + ldv(bb, j);
    }
}

template <typename T>
__global__ __launch_bounds__(256) void add_ln_kernel(
    const int* __restrict__ dflag, int want,
    float* __restrict__ x, const float* __restrict__ t,
    const T* __restrict__ g, const T* __restrict__ bb) {
    GUARD
    int r = blockIdx.x;
    __shared__ float red[10];
    float v[3], sum = 0.f, sq = 0.f;
    for (int i = 0; i < 3; i++) {
        int j = threadIdx.x + i * 256;
        float e = x[(size_t)r * HID + j] + t[(size_t)r * HID + j];
        v[i] = e; sum += e; sq += e * e;
    }
    block_reduce_sum2(sum, sq, red);
    float mu = sum * (1.f / HID);
    float var = sq * (1.f / HID) - mu * mu;
    float inv = 1.f / sqrtf(var + 1e-7f);
    for (int i = 0; i < 3; i++) {
        int j = threadIdx.x + i * 256;
        x[(size_t)r * HID + j] = (v[i] - mu) * inv * ldv(g, j) + ldv(bb, j);
    }
}

// ---------------- bucket index tables ----------------
__device__ int log_bucket(int rel) {
    const int mid = 128;
    if (abs(rel) <= mid) return rel;
    float sign = (rel > 0) ? 1.f : -1.f;
    float abs_pos = fabsf((float)rel);
    float log_pos = ceilf(logf(abs_pos / 128.f) / logf(511.f / 128.f) * 127.f) + 128.f;
    return (int)(log_pos * sign);
}

__global__ void build_idx_kernel(const int* __restrict__ dflag, int want,
                                 int* __restrict__ c2pt, int* __restrict__ p2ct) {
    GUARD
    int i = blockIdx.x * 256 + threadIdx.x;
    if (i >= 1023) return;
    int rel = i - 511;                 // rel = q - k
    int b1 = log_bucket(rel);
    c2pt[i] = min(max(b1 + 256, 0), 511);
    p2ct[i] = min(max(b1 + 256, 0), 511);
}

// ---------------- MFMA GEMM: C[M,N] = A[M,K](f32) @ W[K,N](T) + bias(T) ----------------
// 64x64 tile, BK=64. 4 waves, each 16(m) x 64(n): 4 accum frags of 16x16.
// A fragments: direct global->reg (k-contiguous), split a = a_hi + a_lo (bf16).
// W: staged transposed in LDS as Ws[n][k] (coalesced column-gather + ds_write_b128).
// bf16 weights: C = a_hi*W + a_lo*W (2 mfma/frag).  fp32 weights: + a_hi*W_lo (3 mfma/frag).
template <typename T>
__global__ __launch_bounds__(256) void gemm_mfma(
    const int* __restrict__ dflag, int want,
    const float* __restrict__ A, const T* __restrict__ W, const T* __restrict__ bias,
    float* __restrict__ C, int M, int N, int K) {
    GUARD
    constexpr bool FS = (sizeof(T) == 4);      // fp32 weights need lo part
    constexpr int LROWS = FS ? 64 : 1;
    __shared__ __bf16 Wh[64][72];              // [n][k], 144B rows (9x16B): 2-way alias only
    __shared__ __bf16 Wl[LROWS][72];

    int m0 = blockIdx.y * 64, n0 = blockIdx.x * 64;
    int t = threadIdx.x;
    int lane = t & 63, wm = t >> 6;
    int ln = lane & 15, g = lane >> 4;

    int sn = t & 63, kg = t >> 6;              // staging: column n0+sn, k-rows kg*16..+16
    const float* Arow = A + (size_t)(m0 + wm * 16 + ln) * K;

    f32x4 acc[4];
    for (int f = 0; f < 4; f++) acc[f] = (f32x4){0.f, 0.f, 0.f, 0.f};

    for (int k0 = 0; k0 < K; k0 += 64) {
        // ---- stage W tile (transposed) ----
        {
            bf16x8 h0, h1, l0, l1;
#pragma unroll
            for (int i = 0; i < 8; i++) {
                size_t gi  = (size_t)(k0 + kg * 16 + i) * N + n0 + sn;
                size_t gi2 = (size_t)(k0 + kg * 16 + 8 + i) * N + n0 + sn;
                if constexpr (FS) {
                    float w0 = ((const float*)W)[gi];
                    float w1 = ((const float*)W)[gi2];
                    __bf16 a0 = (__bf16)w0, a1 = (__bf16)w1;
                    h0[i] = a0; l0[i] = (__bf16)(w0 - (float)a0);
                    h1[i] = a1; l1[i] = (__bf16)(w1 - (float)a1);
                } else {
                    h0[i] = __builtin_bit_cast(__bf16, ((const unsigned short*)W)[gi]);
                    h1[i] = __builtin_bit_cast(__bf16, ((const unsigned short*)W)[gi2]);
                }
            }
            *(bf16x8*)&Wh[sn][kg * 16] = h0;
            *(bf16x8*)&Wh[sn][kg * 16 + 8] = h1;
            if constexpr (FS) {
                *(bf16x8*)&Wl[sn][kg * 16] = l0;
                *(bf16x8*)&Wl[sn][kg * 16 + 8] = l1;
            }
        }
        __syncthreads();
        // ---- compute: 2 k-sub-steps of 32 ----
#pragma unroll
        for (int ks = 0; ks < 2; ks++) {
            int ko = ks * 32 + g * 8;
            f32x4 a0 = *(const f32x4*)(Arow + k0 + ko);
            f32x4 a1 = *(const f32x4*)(Arow + k0 + ko + 4);
            bf16x8 ah, al;
#pragma unroll
            for (int j = 0; j < 4; j++) {
                __bf16 hh0 = (__bf16)a0[j];
                ah[j] = hh0; al[j] = (__bf16)(a0[j] - (float)hh0);
                __bf16 hh1 = (__bf16)a1[j];
                ah[j + 4] = hh1; al[j + 4] = (__bf16)(a1[j] - (float)hh1);
            }
#pragma unroll
            for (int f = 0; f < 4; f++) {
                bf16x8 bh = *(const bf16x8*)&Wh[f * 16 + ln][ko];
                acc[f] = mfma16(ah, bh, acc[f]);
                acc[f] = mfma16(al, bh, acc[f]);
                if constexpr (FS) {
                    bf16x8 bl = *(const bf16x8*)&Wl[f * 16 + ln][ko];
                    acc[f] = mfma16(ah, bl, acc[f]);
                }
            }
        }
        __syncthreads();
    }
    // ---- store: D row = g*4+r, col = f*16+ln ----
#pragma unroll
    for (int f = 0; f < 4; f++) {
        int n = n0 + f * 16 + ln;
        float bv = ldv(bias, n);
#pragma unroll
        for (int r = 0; r < 4; r++) {
            int m = m0 + wm * 16 + g * 4 + r;
            C[(size_t)m * N + n] = acc[f][r] + bv;
        }
    }
}

// ---------------- fp32 -> (hi,lo) bf16 split of Q/K buffers ----------------
__global__ __launch_bounds__(256) void qk_convert(
    const int* __restrict__ dflag, int want,
    const float* __restrict__ Qb, const float* __restrict__ Kb,
    __bf16* __restrict__ Qh, __bf16* __restrict__ Ql,
    __bf16* __restrict__ Kh, __bf16* __restrict__ Kl) {
    GUARD
    size_t i = (size_t)blockIdx.x * 256 + threadIdx.x;   // grid covers EXTROWS*HID/8 exactly
    const f32x4* q = (const f32x4*)Qb + i * 2;
    const f32x4* k = (const f32x4*)Kb + i * 2;
    f32x4 q0 = q[0], q1 = q[1], k0 = k[0], k1 = k[1];
    bf16x8 qh, ql, kh, kl;
#pragma unroll
    for (int j = 0; j < 4; j++) {
        __bf16 h;
        h = (__bf16)q0[j]; qh[j] = h;     ql[j] = (__bf16)(q0[j] - (float)h);
        h = (__bf16)q1[j]; qh[j + 4] = h; ql[j + 4] = (__bf16)(q1[j] - (float)h);
        h = (__bf16)k0[j]; kh[j] = h;     kl[j] = (__bf16)(k0[j] - (float)h);
        h = (__bf16)k1[j]; kh[j + 4] = h; kl[j + 4] = (__bf16)(k1[j] - (float)h);
    }
    ((bf16x8*)Qh)[i] = qh; ((bf16x8*)Ql)[i] = ql;
    ((bf16x8*)Kh)[i] = kh; ((bf16x8*)Kl)[i] = kl;
}

// ---------------- MFMA batched NT: C[h][m][n] = sum_d A[am0+m][h*64+d] * B[bm0+n][h*64+d] ----
// Both operands d-contiguous bf16 (hi,lo) -> zero LDS, direct global->frag.
// 3-term split: ah*bh + al*bh + ah*bl.
__global__ __launch_bounds__(256) void bgemm_nt_mfma(
    const int* __restrict__ dflag, int want,
    const __bf16* __restrict__ Ah, const __bf16* __restrict__ Al,
    const __bf16* __restrict__ Bh, const __bf16* __restrict__ Bl,
    float* __restrict__ Cb, int aRow0, int bRow0) {
    GUARD
    int h = blockIdx.z;
    int m0 = blockIdx.y * 64, n0 = blockIdx.x * 64;
    int t = threadIdx.x, lane = t & 63, wm = t >> 6;
    int ln = lane & 15, g = lane >> 4;
    size_t aoff = (size_t)(aRow0 + m0 + wm * 16 + ln) * HID + h * DHEAD;
    f32x4 acc[4];
    for (int f = 0; f < 4; f++) acc[f] = (f32x4){0.f, 0.f, 0.f, 0.f};
#pragma unroll
    for (int ks = 0; ks < 2; ks++) {
        int ko = ks * 32 + g * 8;
        bf16x8 ah = *(const bf16x8*)(Ah + aoff + ko);
        bf16x8 al = *(const bf16x8*)(Al + aoff + ko);
#pragma unroll
        for (int f = 0; f < 4; f++) {
            size_t boff = (size_t)(bRow0 + n0 + f * 16 + ln) * HID + h * DHEAD + ko;
            bf16x8 bh = *(const bf16x8*)(Bh + boff);
            bf16x8 bl = *(const bf16x8*)(Bl + boff);
            acc[f] = mfma16(ah, bh, acc[f]);
            acc[f] = mfma16(al, bh, acc[f]);
            acc[f] = mfma16(ah, bl, acc[f]);
        }
    }
    float* Cp = Cb + (size_t)h * SEQ * SPAN2;
#pragma unroll
    for (int f = 0; f < 4; f++)
#pragma unroll
        for (int r = 0; r < 4; r++)
            Cp[(size_t)(m0 + wm * 16 + g * 4 + r) * SPAN2 + n0 + f * 16 + ln] = acc[f][r];
}

// ---------------- assemble + softmax (in place over sc), per batch b ----------------
__global__ __launch_bounds__(256) void attn_softmax_kernel(
    const int* __restrict__ dflag, int want,
    float* __restrict__ sc, const float* __restrict__ c2p, const float* __restrict__ p2c,
    const int* __restrict__ c2pt, const int* __restrict__ p2ct,
    const int* __restrict__ amask, int b) {
    GUARD
    int q = blockIdx.x & 511;
    int h = blockIdx.x >> 9;
    float* row = sc + ((size_t)h * SEQ + q) * SPAN2;
    const float* c2pr = c2p + ((size_t)h * SEQ + q) * SPAN2;
    const float* p2cb = p2c + (size_t)h * SEQ * SPAN2;
    int mq = amask[b * SEQ + q];
    __shared__ float red[10];
    float s[2];
    float mx = NEG_BIG;
    for (int i = 0; i < 2; i++) {
        int k = threadIdx.x + i * 256;
        int d = q - k + 511;
        float val = (row[k] + c2pr[c2pt[d]] + p2cb[(size_t)k * SPAN2 + p2ct[d]]) * ATT_SCALE;
        int mk = amask[b * SEQ + k];
        val = (mq && mk) ? val : NEG_BIG;
        s[i] = val;
        mx = fmaxf(mx, val);
    }
    mx = block_max(mx, red);
    float lsum = 0.f;
    float e[2];
    for (int i = 0; i < 2; i++) { e[i] = expf(s[i] - mx); lsum += e[i]; }
    float tot = block_sum(lsum, red);
    float rinv = 1.f / tot;
    for (int i = 0; i < 2; i++) {
        int k = threadIdx.x + i * 256;
        row[k] = e[i] * rinv;
    }
}

// ---------------- probs @ V -> ctx rows b*SEQ.. of Cout[2048,768] ----------------
__global__ __launch_bounds__(256) void bgemm_pv(
    const int* __restrict__ dflag, int want,
    const float* __restrict__ P, const float* __restrict__ Vb, float* __restrict__ Cout, int b) {
    GUARD
    int h = blockIdx.y;
    int m0 = blockIdx.x * 64;
    const float* Pp = P + (size_t)h * SEQ * SPAN2;
    __shared__ float Ps[64][65];   // [k][m]
    __shared__ float Vs[64][65];   // [k][n]
    int tn = threadIdx.x & 15, tm = threadIdx.x >> 4;
    float acc[4][4] = {};
    for (int k0 = 0; k0 < SEQ; k0 += 64) {
        for (int i = 0; i < 16; i++) {
            int idx = threadIdx.x + i * 256;
            int r = idx >> 6, c = idx & 63;
            Ps[c][r] = Pp[(size_t)(m0 + r) * SPAN2 + k0 + c];
            Vs[r][c] = Vb[(size_t)(b * SEQ + k0 + r) * HID + h * DHEAD + c];
        }
        __syncthreads();
        for (int k = 0; k < 64; k++) {
            float a[4], w[4];
            for (int i = 0; i < 4; i++) a[i] = Ps[k][tm * 4 + i];
            for (int j = 0; j < 4; j++) w[j] = Vs[k][tn * 4 + j];
            for (int i = 0; i < 4; i++)
                for (int j = 0; j < 4; j++) acc[i][j] += a[i] * w[j];
        }
        __syncthreads();
    }
    for (int i = 0; i < 4; i++)
        for (int j = 0; j < 4; j++)
            Cout[(size_t)(b * SEQ + m0 + tm * 4 + i) * HID + h * DHEAD + tn * 4 + j] = acc[i][j];
}

// ---------------- GELU (exact erf) ----------------
__global__ __launch_bounds__(256) void gelu_kernel(const int* __restrict__ dflag, int want,
                                                   float* __restrict__ p, int n4) {
    GUARD
    int i = blockIdx.x * 256 + threadIdx.x;
    if (i >= n4) return;
    float4 v = ((float4*)p)[i];
    v.x = 0.5f * v.x * (1.f + erff(v.x * 0.70710678118654752f));
    v.y = 0.5f * v.y * (1.f + erff(v.y * 0.70710678118654752f));
    v.z = 0.5f * v.z * (1.f + erff(v.z * 0.70710678118654752f));
    v.w = 0.5f * v.w * (1.f + erff(v.w * 0.70710678118654752f));
    ((float4*)p)[i] = v;
}

// ---------------- classifier ----------------
template <typename T>
__global__ __launch_bounds__(64) void cls_kernel(
    const int* __restrict__ dflag, int want,
    const float* __restrict__ x, const T* __restrict__ w, const T* __restrict__ bias,
    T* __restrict__ out) {
    GUARD
    int r = blockIdx.x;
    int t = threadIdx.x;
    float acc[NCLS] = {};
    for (int k = t; k < HID; k += 64) {
        float xv = x[(size_t)r * HID + k];
        for (int c = 0; c < NCLS; c++) acc[c] += xv * ldv(w, (size_t)k * NCLS + c);
    }
    for (int off = 32; off > 0; off >>= 1)
        for (int c = 0; c < NCLS; c++) acc[c] += __shfl_down(acc[c], off, 64);
    if (t == 0)
        for (int c = 0; c < NCLS; c++)
            stv(out, (size_t)r * NCLS + c, acc[c] + ldv(bias, c));
}

// ---------------- templated whole-model launcher ----------------
template <typename T>
static void run_model(void* const* d_in, void* d_out,
                      float* xbuf, float* Qb, float* Kb, float* Vb, float* tmp,
                      float* sc, float* c2p, float* p2c, float* mid,
                      int* c2pt, int* p2ct, const int* dflag,
                      __bf16* Qh, __bf16* Ql, __bf16* Kh, __bf16* Kl,
                      hipStream_t stream) {
    const int W = WantFlag<T>::v;
    const int* input_ids = (const int*)d_in[0];
    const int* amask     = (const int*)d_in[1];
    const T* word_emb = (const T*)d_in[2];
    const T* tok_emb  = (const T*)d_in[3];
    const T* emb_ln_s = (const T*)d_in[4];
    const T* emb_ln_b = (const T*)d_in[5];
    const T* rel_emb  = (const T*)d_in[6];
    const T* rel_ln_s = (const T*)d_in[7];
    const T* rel_ln_b = (const T*)d_in[8];
    const T* q_w  = (const T*)d_in[9];
    const T* q_b  = (const T*)d_in[10];
    const T* k_w  = (const T*)d_in[11];
    const T* k_b  = (const T*)d_in[12];
    const T* v_w  = (const T*)d_in[13];
    const T* v_b  = (const T*)d_in[14];
    const T* ao_w = (const T*)d_in[15];
    const T* ao_b = (const T*)d_in[16];
    const T* a_ln_s = (const T*)d_in[17];
    const T* a_ln_b = (const T*)d_in[18];
    const T* i_w  = (const T*)d_in[19];
    const T* i_b  = (const T*)d_in[20];
    const T* o_w  = (const T*)d_in[21];
    const T* o_b  = (const T*)d_in[22];
    const T* o_ln_s = (const T*)d_in[23];
    const T* o_ln_b = (const T*)d_in[24];
    const T* cls_w = (const T*)d_in[25];
    const T* cls_b = (const T*)d_in[26];
    T* out = (T*)d_out;

    embed_ln_kernel<T><<<NTOK, 256, 0, stream>>>(dflag, W, input_ids, amask, word_emb,
                                                 tok_emb, emb_ln_s, emb_ln_b, xbuf);
    rel_ln_kernel<T><<<SEQ, 256, 0, stream>>>(dflag, W, rel_emb, rel_ln_s, rel_ln_b, xbuf);
    build_idx_kernel<<<4, 256, 0, stream>>>(dflag, W, c2pt, p2ct);

    dim3 g_qk(HID / 64, EXTROWS / 64);      // (12,40)
    dim3 g_v(HID / 64, NTOK / 64);          // (12,32)
    dim3 g_nt(8, 8, NHEADS);                // 64x64 tiles over 512x512, 12 heads
    dim3 g_pv(8, NHEADS);
    dim3 g_ff1(FFDIM / 64, NTOK / 64);      // (48,32)
    dim3 g_ff2(HID / 64, NTOK / 64);
    int cvt_blocks = (EXTROWS * HID / 8) / 256;   // 960, exact

    for (int l = 0; l < NLAYER; l++) {
        const T* qw = q_w + (size_t)l * HID * HID;
        const T* kw = k_w + (size_t)l * HID * HID;
        const T* vw = v_w + (size_t)l * HID * HID;
        const T* aw = ao_w + (size_t)l * HID * HID;
        const T* iw = i_w + (size_t)l * HID * FFDIM;
        const T* ow = o_w + (size_t)l * FFDIM * HID;

        gemm_mfma<T><<<g_qk, 256, 0, stream>>>(dflag, W, xbuf, qw, q_b + (size_t)l * HID, Qb, EXTROWS, HID, HID);
        gemm_mfma<T><<<g_qk, 256, 0, stream>>>(dflag, W, xbuf, kw, k_b + (size_t)l * HID, Kb, EXTROWS, HID, HID);
        gemm_mfma<T><<<g_v, 256, 0, stream>>>(dflag, W, xbuf, vw, v_b + (size_t)l * HID, Vb, NTOK, HID, HID);

        qk_convert<<<cvt_blocks, 256, 0, stream>>>(dflag, W, Qb, Kb, Qh, Ql, Kh, Kl);

        for (int b = 0; b < BATCH; b++) {
            bgemm_nt_mfma<<<g_nt, 256, 0, stream>>>(dflag, W, Qh, Ql, Kh, Kl, sc,  b * SEQ, b * SEQ);  // qk
            bgemm_nt_mfma<<<g_nt, 256, 0, stream>>>(dflag, W, Qh, Ql, Kh, Kl, c2p, b * SEQ, NTOK);     // q . pk
            bgemm_nt_mfma<<<g_nt, 256, 0, stream>>>(dflag, W, Kh, Kl, Qh, Ql, p2c, b * SEQ, NTOK);     // k . pq
            attn_softmax_kernel<<<NHEADS * SEQ, 256, 0, stream>>>(dflag, W, sc, c2p, p2c,
                                                                  c2pt, p2ct, amask, b);
            bgemm_pv<<<g_pv, 256, 0, stream>>>(dflag, W, sc, Vb, Qb, b);  // ctx rows b*SEQ..
        }

        gemm_mfma<T><<<g_v, 256, 0, stream>>>(dflag, W, Qb, aw, ao_b + (size_t)l * HID, tmp, NTOK, HID, HID);
        add_ln_kernel<T><<<NTOK, 256, 0, stream>>>(dflag, W, xbuf, tmp,
                                                   a_ln_s + (size_t)l * HID, a_ln_b + (size_t)l * HID);

        gemm_mfma<T><<<g_ff1, 256, 0, stream>>>(dflag, W, xbuf, iw, i_b + (size_t)l * FFDIM, mid, NTOK, FFDIM, HID);
        gelu_kernel<<<(NTOK * FFDIM / 4 + 255) / 256, 256, 0, stream>>>(dflag, W, mid, NTOK * FFDIM / 4);
        gemm_mfma<T><<<g_ff2, 256, 0, stream>>>(dflag, W, mid, ow, o_b + (size_t)l * HID, tmp, NTOK, HID, FFDIM);
        add_ln_kernel<T><<<NTOK, 256, 0, stream>>>(dflag, W, xbuf, tmp,
                                                   o_ln_s + (size_t)l * HID, o_ln_b + (size_t)l * HID);
    }

    cls_kernel<T><<<NTOK, 64, 0, stream>>>(dflag, W, xbuf, cls_w, cls_b, out);
}

// ---------------- host entry ----------------
extern "C" void kernel_launch(void* const* d_in, const int* in_sizes, int n_in,
                              void* d_out, int out_size, void* d_ws, size_t ws_size,
                              hipStream_t stream) {
    // workspace layout (floats) — ~74 MB fp32 region + 15.7 MB bf16 hi/lo region
    const size_t XBUF_F = (size_t)EXTROWS * HID;                 // 1,966,080
    const size_t VB_F   = (size_t)NTOK * HID;                    // 1,572,864
    const size_t SC_F   = (size_t)NHEADS * SEQ * SPAN2;          // 3,145,728 (per batch)
    float* xbuf = (float*)d_ws;
    float* Qb   = xbuf + XBUF_F;
    float* Kb   = Qb + XBUF_F;
    float* Vb   = Kb + XBUF_F;
    float* tmp  = Vb + VB_F;
    float* sc   = tmp + VB_F;
    float* c2p  = sc + SC_F;
    float* p2c  = c2p + SC_F;
    float* mid  = sc;                       // alias: FFN mid (6,291,456 f) spans sc+c2p; phase-disjoint
    int* c2pt   = (int*)(p2c + SC_F);
    int* p2ct   = c2pt + 1024;
    int* dflag  = p2ct + 1024;
    __bf16* Qh  = (__bf16*)(dflag + 16);    // 16B-aligned; 4 x EXTROWS*HID bf16
    __bf16* Ql  = Qh + XBUF_F;
    __bf16* Kh  = Ql + XBUF_F;
    __bf16* Kl  = Kh + XBUF_F;

    detect_kernel<<<1, 64, 0, stream>>>(d_in[4], dflag);   // emb_ln_s == ones

    run_model<bf16>(d_in, d_out, xbuf, Qb, Kb, Vb, tmp, sc, c2p, p2c, mid,
                    c2pt, p2ct, dflag, Qh, Ql, Kh, Kl, stream);
    run_model<float>(d_in, d_out, xbuf, Qb, Kb, Vb, tmp, sc, c2p, p2c, mid,
                     c2pt, p2ct, dflag, Qh, Ql, Kh, Kl, stream);
}